// Round 1
// baseline (986.959 us; speedup 1.0000x reference)
//
#include <hip/hip_runtime.h>
#include <hip/hip_bf16.h>
#include <stdint.h>

// Problem: act (8192 x 4096) f32, w (4096 x 8192) f32 -> out (8192 x 8192) f32
#define BDIM 8192   // batch rows
#define CIN  4096
#define COUT 8192
#define EPSQ 1e-6f

typedef int v4i __attribute__((ext_vector_type(4)));

#define GLD16_TO_LDS(gp, lp)                                                   \
    __builtin_amdgcn_global_load_lds(                                          \
        (const __attribute__((address_space(1))) void*)(gp),                   \
        (__attribute__((address_space(3))) void*)(lp), 16, 0, 0)

__device__ __forceinline__ int q8i(float x) {
    float r = rintf(x);                 // round-half-to-even == jnp.round
    r = fminf(127.0f, fmaxf(-127.0f, r));
    return (int)r;
}

// ---------------------------------------------------------------------------
// Kernel 1: per-column absmax of act via atomicMax on float bits.
// Candidates are |x| >= 0 so their int bit patterns order like floats, and the
// 0xAAAAAAAA workspace poison is negative -> no init pass needed.
// grid (4, 64), block 256. Each thread owns one float4 column group, 128 rows.
__global__ void act_absmax_kernel(const float* __restrict__ act,
                                  int* __restrict__ amax_bits) {
    int c4 = (blockIdx.x << 8) + threadIdx.x;   // 0..1023
    int r0 = blockIdx.y << 7;                   // 128 rows/block
    const float4* p = (const float4*)act + (size_t)r0 * (CIN / 4) + c4;
    float mx = 0.f, my = 0.f, mz = 0.f, mw = 0.f;
#pragma unroll 4
    for (int r = 0; r < 128; ++r) {
        float4 v = p[(size_t)r * (CIN / 4)];
        mx = fmaxf(mx, fabsf(v.x));
        my = fmaxf(my, fabsf(v.y));
        mz = fmaxf(mz, fabsf(v.z));
        mw = fmaxf(mw, fabsf(v.w));
    }
    int c = c4 << 2;
    atomicMax(amax_bits + c + 0, __float_as_int(mx));
    atomicMax(amax_bits + c + 1, __float_as_int(my));
    atomicMax(amax_bits + c + 2, __float_as_int(mz));
    atomicMax(amax_bits + c + 3, __float_as_int(mw));
}

// ---------------------------------------------------------------------------
// Kernel 2: quantize act -> int8 (k-contiguous), and write inv_as = 1/act_scale
// (replicating the reference's 1.0/ (127/bound) double division bitwise).
// One thread per float4. grid 32768, block 256.
__global__ void act_quant_kernel(const float4* __restrict__ act4,
                                 const int4* __restrict__ amax_bits4,
                                 float* __restrict__ inv_as,
                                 int* __restrict__ actq_packed) {
    int flat4 = blockIdx.x * 256 + threadIdx.x;       // float4 index
    int c4 = flat4 & ((CIN / 4) - 1);                 // float4 col group
    float4 v = act4[flat4];
    int4 mb = amax_bits4[c4];
    float sx = 127.0f / (__int_as_float(mb.x) + EPSQ);
    float sy = 127.0f / (__int_as_float(mb.y) + EPSQ);
    float sz = 127.0f / (__int_as_float(mb.z) + EPSQ);
    float sw = 127.0f / (__int_as_float(mb.w) + EPSQ);
    int q0 = q8i(v.x * sx), q1 = q8i(v.y * sy), q2 = q8i(v.z * sz), q3 = q8i(v.w * sw);
    int packed = (q0 & 0xff) | ((q1 & 0xff) << 8) | ((q2 & 0xff) << 16) | ((q3 & 0xff) << 24);
    actq_packed[flat4] = packed;
    if (flat4 < CIN / 4) {   // row 0: also emit inv act scale
        int c = c4 << 2;
        inv_as[c + 0] = 1.0f / sx;
        inv_as[c + 1] = 1.0f / sy;
        inv_as[c + 2] = 1.0f / sz;
        inv_as[c + 3] = 1.0f / sw;
    }
}

// ---------------------------------------------------------------------------
// Kernel 3: per-output-column absmax of w_scaled = w * inv_as[k].
// grid (8, 64), block 256. Thread owns one float4 col group, 64 k-rows.
__global__ void w_absmax_kernel(const float* __restrict__ w,
                                const float* __restrict__ inv_as,
                                int* __restrict__ wmax_bits) {
    int c4 = (blockIdx.x << 8) + threadIdx.x;   // 0..2047
    int k0 = blockIdx.y << 6;                   // 64 rows/block
    const float4* p = (const float4*)w + (size_t)k0 * (COUT / 4) + c4;
    float mx = 0.f, my = 0.f, mz = 0.f, mw = 0.f;
#pragma unroll 4
    for (int r = 0; r < 64; ++r) {
        float ia = inv_as[k0 + r];
        float4 v = p[(size_t)r * (COUT / 4)];
        mx = fmaxf(mx, fabsf(v.x * ia));
        my = fmaxf(my, fabsf(v.y * ia));
        mz = fmaxf(mz, fabsf(v.z * ia));
        mw = fmaxf(mw, fabsf(v.w * ia));
    }
    int c = c4 << 2;
    atomicMax(wmax_bits + c + 0, __float_as_int(mx));
    atomicMax(wmax_bits + c + 1, __float_as_int(my));
    atomicMax(wmax_bits + c + 2, __float_as_int(mz));
    atomicMax(wmax_bits + c + 3, __float_as_int(mw));
}

// ---------------------------------------------------------------------------
// Kernel 4: quantize w and transpose to w_qT (COUT x CIN, k-contiguous int8).
// 64(k) x 64(j) tile through LDS. grid (64, 128), block 256.
__global__ void w_quant_t_kernel(const float* __restrict__ w,
                                 const float* __restrict__ inv_as,
                                 const int* __restrict__ wmax_bits,
                                 signed char* __restrict__ wqT) {
    __shared__ int tile32[16][65];   // [k/4 within tile][j within tile]
    int t = threadIdx.x;
    int k0 = blockIdx.x << 6;
    int j0 = blockIdx.y << 6;
    int tx = t & 63;      // j offset
    int ty = t >> 6;      // 0..3
    int j = j0 + tx;
    float wscale = 127.0f / (__int_as_float(wmax_bits[j]) + EPSQ);
#pragma unroll
    for (int r = 0; r < 4; ++r) {
        int a = r * 4 + ty;            // k-quad index 0..15
        int kb = k0 + (a << 2);
        int packed = 0;
#pragma unroll
        for (int u = 0; u < 4; ++u) {
            int k = kb + u;
            float wsc = w[(size_t)k * COUT + j] * inv_as[k];  // == w_scaled bitwise
            int q = q8i(wsc * wscale);
            packed |= (q & 0xff) << (8 * u);
        }
        tile32[a][tx] = packed;
    }
    __syncthreads();
    // write out: 64 rows of 64 bytes; thread -> (j_loc = t>>2, 16B chunk c = t&3)
    int j_loc = t >> 2;
    int c = t & 3;
    int4 v;
    v.x = tile32[c * 4 + 0][j_loc];
    v.y = tile32[c * 4 + 1][j_loc];
    v.z = tile32[c * 4 + 2][j_loc];
    v.w = tile32[c * 4 + 3][j_loc];
    *(int4*)(wqT + (size_t)(j0 + j_loc) * CIN + k0 + c * 16) = v;
}

// ---------------------------------------------------------------------------
// Kernel 5: int8 NT GEMM (A: BDIM x CIN, B = w_qT: COUT x CIN) + dequant.
// 128x128 block tile, BK=64, 4 waves each computing 64x64 via 4x4 of
// mfma_i32_16x16x64_i8. LDS is fragment-major: chunk c = g*128 + m holds
// 16 bytes A[m][k0+g*16 .. +15] -> global_load_lds writes and ds_read_b128
// fragment reads are both contiguous / conflict-free (2-way max).
__global__ __launch_bounds__(256) void gemm_i8_kernel(
    const signed char* __restrict__ Aq,
    const signed char* __restrict__ Bq,
    const int* __restrict__ wmax_bits,
    float* __restrict__ out) {
    __shared__ __align__(16) signed char As[128 * 64];
    __shared__ __align__(16) signed char Bs[128 * 64];

    const int tid = threadIdx.x;
    const int wave = tid >> 6;
    const int lane = tid & 63;
    const int bm = blockIdx.y << 7;
    const int bn = blockIdx.x << 7;
    const int wm = (wave >> 1) << 6;   // wave row offset within block tile
    const int wn = (wave & 1) << 6;    // wave col offset

    const int g = lane >> 4;           // k-group 0..3
    const int l16 = lane & 15;

    v4i acc[4][4] = {};

    for (int kt = 0; kt < CIN; kt += 64) {
        __syncthreads();
        // stage: wave w loads g-column w; m = t*64 + lane
#pragma unroll
        for (int t = 0; t < 2; ++t) {
            int c0 = (wave * 2 + t) * 64;          // chunk base (wave-uniform)
            int mm = (t << 6) + lane;              // m within tile (c0&127 + lane)
            int gg = wave;                         // k-group for this wave
            const signed char* ga = Aq + ((size_t)(bm + mm) << 12) + kt + (gg << 4);
            GLD16_TO_LDS(ga, As + (c0 << 4));
            const signed char* gb = Bq + ((size_t)(bn + mm) << 12) + kt + (gg << 4);
            GLD16_TO_LDS(gb, Bs + (c0 << 4));
        }
        __syncthreads();

        v4i af[4], bf[4];
#pragma unroll
        for (int t = 0; t < 4; ++t)
            af[t] = *(const v4i*)(As + (((g << 7) + wm + (t << 4) + l16) << 4));
#pragma unroll
        for (int t = 0; t < 4; ++t)
            bf[t] = *(const v4i*)(Bs + (((g << 7) + wn + (t << 4) + l16) << 4));

#pragma unroll
        for (int tm = 0; tm < 4; ++tm)
#pragma unroll
            for (int tn = 0; tn < 4; ++tn)
                acc[tm][tn] = __builtin_amdgcn_mfma_i32_16x16x64_i8(
                    af[tm], bf[tn], acc[tm][tn], 0, 0, 0);
    }

    // epilogue: dequant by 1/w_scale (recomputed exactly as reference ops)
#pragma unroll
    for (int tn = 0; tn < 4; ++tn) {
        int col = bn + wn + (tn << 4) + l16;
        float wscale = 127.0f / (__int_as_float(wmax_bits[col]) + EPSQ);
        float invws = 1.0f / wscale;
#pragma unroll
        for (int tm = 0; tm < 4; ++tm) {
            int row0 = bm + wm + (tm << 4) + (g << 2);
#pragma unroll
            for (int r = 0; r < 4; ++r)
                out[((size_t)(row0 + r) << 13) + col] = (float)acc[tm][tn][r] * invws;
        }
    }
}

// ---------------------------------------------------------------------------
extern "C" void kernel_launch(void* const* d_in, const int* in_sizes, int n_in,
                              void* d_out, int out_size, void* d_ws, size_t ws_size,
                              hipStream_t stream) {
    const float* act = (const float*)d_in[0];
    const float* w   = (const float*)d_in[1];
    float* out = (float*)d_out;
    char* ws = (char*)d_ws;

    // workspace layout (~64.06 MB)
    int*   amax_bits = (int*)ws;                                   // 4096 ints
    float* inv_as    = (float*)(ws + 16384);                       // 4096 floats
    int*   wmax_bits = (int*)(ws + 32768);                         // 8192 ints
    signed char* actq = (signed char*)(ws + 65536);                // 8192*4096
    signed char* wqT  = (signed char*)(ws + 65536 + (size_t)BDIM * CIN); // 8192*4096

    act_absmax_kernel<<<dim3(4, 64), 256, 0, stream>>>(act, amax_bits);
    act_quant_kernel<<<(BDIM * CIN / 4) / 256, 256, 0, stream>>>(
        (const float4*)act, (const int4*)amax_bits, inv_as, (int*)actq);
    w_absmax_kernel<<<dim3(8, 64), 256, 0, stream>>>(w, inv_as, wmax_bits);
    w_quant_t_kernel<<<dim3(64, 128), 256, 0, stream>>>(w, inv_as, wmax_bits, wqT);
    gemm_i8_kernel<<<dim3(COUT / 128, BDIM / 128), 256, 0, stream>>>(
        actq, wqT, wmax_bits, out);
}